// Round 5
// baseline (7658.212 us; speedup 1.0000x reference)
//
#include <hip/hip_runtime.h>
#include <hip/hip_cooperative_groups.h>
#include <math.h>

namespace cg = cooperative_groups;

#define Cdim 512
#define CRdim 32
#define Ldim 4096
#define Bdim 64
#define NROWS (Bdim * Cdim)   // 32768

typedef float f32x4 __attribute__((ext_vector_type(4)));

// One cooperative kernel. Per iteration each block owns one (b,c) row:
//   phase 1: stream row HBM->LDS, reduce to mean[row]
//   grid.sync()
//   phase 2: redundant tiny MLP (weights L2-hot), scale LDS row, nt-store out
// x is read from HBM exactly once.
__global__ __launch_bounds__(256) void se_fused(
        const float* __restrict__ x,
        const float* __restrict__ w1, const float* __restrict__ b1,
        const float* __restrict__ w2, const float* __restrict__ b2,
        float* __restrict__ out, float* __restrict__ mean)
{
    cg::grid_group grid = cg::this_grid();
    __shared__ float rowbuf[Ldim];         // 16 KiB
    __shared__ float red[4];
    __shared__ float hpart[CRdim][8];
    __shared__ float hvec[CRdim];
    __shared__ float sval;

    const int t = threadIdx.x;
    const int G = gridDim.x;               // multiple of 512
    const int niter = (NROWS + G - 1) / G;

    for (int it = 0; it < niter; ++it) {
        const int row = it * G + blockIdx.x;
        const bool active = row < NROWS;
        f32x4* rb = (f32x4*)rowbuf;

        if (active) {
            const f32x4* xr = (const f32x4*)(x + (size_t)row * Ldim);
            float s = 0.f;
#pragma unroll
            for (int k = 0; k < 4; ++k) {
                f32x4 v = __builtin_nontemporal_load(&xr[t + k * 256]);
                rb[t + k * 256] = v;
                s += (v.x + v.y) + (v.z + v.w);
            }
#pragma unroll
            for (int off = 32; off > 0; off >>= 1) s += __shfl_down(s, off, 64);
            if ((t & 63) == 0) red[t >> 6] = s;
            __syncthreads();
            if (t == 0)
                mean[row] = (red[0] + red[1] + red[2] + red[3]) * (1.0f / Ldim);
        }
        __threadfence();                   // means visible device-wide
        grid.sync();

        if (active) {
            const int b = row >> 9;        // row / 512
            const int c = row & 511;
            // h = relu(W1 @ m + b1): 32 outputs x 8 slices of 64 channels
            const int hidx = t >> 3;       // 0..31
            const int slice = t & 7;       // 0..7
            const f32x4* mv = (const f32x4*)(mean + b * Cdim + slice * 64);
            const f32x4* wv = (const f32x4*)(w1 + hidx * Cdim + slice * 64);
            f32x4 a4 = {0.f, 0.f, 0.f, 0.f};
#pragma unroll
            for (int j = 0; j < 16; ++j) a4 += mv[j] * wv[j];
            hpart[hidx][slice] = (a4.x + a4.y) + (a4.z + a4.w);
            __syncthreads();
            if (t < CRdim) {
                float a = b1[t];
#pragma unroll
                for (int j = 0; j < 8; ++j) a += hpart[t][j];
                hvec[t] = fmaxf(a, 0.f);
            }
            __syncthreads();
            if (t == 0) {
                float a = b2[c];
                const float* w2r = w2 + c * CRdim;
#pragma unroll
                for (int r = 0; r < CRdim; ++r) a = fmaf(hvec[r], w2r[r], a);
                sval = 1.0f / (1.0f + expf(-a));
            }
            __syncthreads();
            const float sc = sval;
            f32x4* orow = (f32x4*)(out + (size_t)row * Ldim);
#pragma unroll
            for (int k = 0; k < 4; ++k) {
                f32x4 v = rb[t + k * 256];
                v *= sc;
                __builtin_nontemporal_store(v, &orow[t + k * 256]);
            }
        }
    }
}

extern "C" void kernel_launch(void* const* d_in, const int* in_sizes, int n_in,
                              void* d_out, int out_size, void* d_ws, size_t ws_size,
                              hipStream_t stream) {
    const float* x  = (const float*)d_in[0];
    const float* w1 = (const float*)d_in[1];
    const float* b1 = (const float*)d_in[2];
    const float* w2 = (const float*)d_in[3];
    const float* b2 = (const float*)d_in[4];
    float* out  = (float*)d_out;
    float* mean = (float*)d_ws;            // 32768 floats

    // Size grid to guaranteed co-residency, floored to a multiple of 512 so
    // each iteration covers whole batches (phase 2 needs a full batch's means).
    int blocksPerCU = 0;
    (void)hipOccupancyMaxActiveBlocksPerMultiprocessor(&blocksPerCU, (const void*)se_fused, 256, 0);
    if (blocksPerCU < 1) blocksPerCU = 1;
    hipDeviceProp_t prop;
    int dev = 0;
    (void)hipGetDevice(&dev);
    (void)hipGetDeviceProperties(&prop, dev);
    long long cap = (long long)blocksPerCU * prop.multiProcessorCount;
    long long G = (cap / 512) * 512;
    if (G < 512) G = 512;
    if (G > NROWS) G = NROWS;

    void* args[] = {(void*)&x, (void*)&w1, (void*)&b1, (void*)&w2, (void*)&b2,
                    (void*)&out, (void*)&mean};
    (void)hipLaunchCooperativeKernel((const void*)se_fused, dim3((int)G), dim3(256),
                                     args, 0, stream);
}

// Round 6
// 2699.714 us; speedup vs baseline: 2.8367x; 2.8367x over previous
//
#include <hip/hip_runtime.h>
#include <math.h>

#define Cdim 512
#define CRdim 32
#define Ldim 4096
#define Bdim 64
#define NROWS (Bdim * Cdim)   // 32768

typedef float f32x4 __attribute__((ext_vector_type(4)));

// Single-pass SE: each block owns one (b,c) row per iteration.
//   1) stream row HBM->LDS (nt loads), reduce -> mean[row], release-add cnt[b]
//   2) acquire-spin until cnt[b]==512 (all rows of batch b done; co-resident)
//   3) redundant tiny MLP from L2-hot mean/weights -> s(b,c)
//   4) scale LDS row, nt-store to out
// x is read from HBM exactly once; no grid-wide barrier.
__global__ __launch_bounds__(256) void se_fused(
        const float* __restrict__ x,
        const float* __restrict__ w1, const float* __restrict__ b1,
        const float* __restrict__ w2, const float* __restrict__ b2,
        float* __restrict__ out, float* __restrict__ mean,
        unsigned int* __restrict__ cnt)
{
    __shared__ float rowbuf[Ldim];         // 16 KiB
    __shared__ float red[4];
    __shared__ float hvec[CRdim];
    __shared__ float sval;

    const int t = threadIdx.x;
    const int G = gridDim.x;               // multiple of 512
    const int niter = (NROWS + G - 1) / G;

    for (int it = 0; it < niter; ++it) {
        const int row = it * G + blockIdx.x;
        if (row >= NROWS) continue;        // uniform per block
        const int b = row >> 9;
        const int c = row & 511;
        f32x4* rb = (f32x4*)rowbuf;

        // ---- phase 1: load + reduce ----
        const f32x4* xr = (const f32x4*)(x + (size_t)row * Ldim);
        float s = 0.f;
#pragma unroll
        for (int k = 0; k < 4; ++k) {
            f32x4 v = __builtin_nontemporal_load(&xr[t + k * 256]);
            rb[t + k * 256] = v;
            s += (v.x + v.y) + (v.z + v.w);
        }
#pragma unroll
        for (int off = 32; off > 0; off >>= 1) s += __shfl_down(s, off, 64);
        if ((t & 63) == 0) red[t >> 6] = s;
        __syncthreads();
        if (t == 0) {
            mean[row] = (red[0] + red[1] + red[2] + red[3]) * (1.0f / Ldim);
            // release: mean[row] visible device-wide before the count bump
            __hip_atomic_fetch_add(&cnt[b], 1u, __ATOMIC_RELEASE,
                                   __HIP_MEMORY_SCOPE_AGENT);
            // ---- phase 2: wait for this batch's 512 means ----
            while (__hip_atomic_load(&cnt[b], __ATOMIC_ACQUIRE,
                                     __HIP_MEMORY_SCOPE_AGENT) < (unsigned)Cdim)
                __builtin_amdgcn_s_sleep(2);
        }
        __syncthreads();

        // ---- phase 3: redundant tiny MLP ----
        if (t < CRdim) {
            const f32x4* mv = (const f32x4*)(mean + b * Cdim);
            const f32x4* wv = (const f32x4*)(w1 + t * Cdim);
            f32x4 a0 = {0.f,0.f,0.f,0.f}, a1 = {0.f,0.f,0.f,0.f};
            f32x4 a2 = {0.f,0.f,0.f,0.f}, a3 = {0.f,0.f,0.f,0.f};
#pragma unroll
            for (int j = 0; j < 128; j += 4) {
                a0 += mv[j]   * wv[j];
                a1 += mv[j+1] * wv[j+1];
                a2 += mv[j+2] * wv[j+2];
                a3 += mv[j+3] * wv[j+3];
            }
            f32x4 a = (a0 + a1) + (a2 + a3);
            hvec[t] = fmaxf(b1[t] + (a.x + a.y) + (a.z + a.w), 0.f);
        }
        __syncthreads();
        if (t == 0) {
            float a = b2[c];
            const float* w2r = w2 + c * CRdim;
#pragma unroll
            for (int r = 0; r < CRdim; ++r) a = fmaf(hvec[r], w2r[r], a);
            sval = 1.0f / (1.0f + expf(-a));
        }
        __syncthreads();

        // ---- phase 4: scale + store ----
        const float sc = sval;
        f32x4* orow = (f32x4*)(out + (size_t)row * Ldim);
#pragma unroll
        for (int k = 0; k < 4; ++k) {
            f32x4 v = rb[t + k * 256];
            v *= sc;
            __builtin_nontemporal_store(v, &orow[t + k * 256]);
        }
        __syncthreads();                   // rowbuf reuse safety
    }
}

extern "C" void kernel_launch(void* const* d_in, const int* in_sizes, int n_in,
                              void* d_out, int out_size, void* d_ws, size_t ws_size,
                              hipStream_t stream) {
    const float* x  = (const float*)d_in[0];
    const float* w1 = (const float*)d_in[1];
    const float* b1 = (const float*)d_in[2];
    const float* w2 = (const float*)d_in[3];
    const float* b2 = (const float*)d_in[4];
    float* out  = (float*)d_out;

    float* mean = (float*)d_ws;                       // 32768 floats
    unsigned int* cnt = (unsigned int*)(mean + NROWS);  // 64 uints

    // counters must be zero at kernel start every call (ws is not re-poisoned)
    hipMemsetAsync(cnt, 0, Bdim * sizeof(unsigned int), stream);

    int bpc = 0;
    (void)hipOccupancyMaxActiveBlocksPerMultiprocessor(&bpc, (const void*)se_fused, 256, 0);
    if (bpc < 1) bpc = 1;
    hipDeviceProp_t prop;
    int dev = 0;
    (void)hipGetDevice(&dev);
    (void)hipGetDeviceProperties(&prop, dev);
    long long cap = (long long)bpc * prop.multiProcessorCount;
    long long G = (cap / 512) * 512;                  // whole batches per iteration
    if (G < 512) G = 512;
    if (G > NROWS) G = NROWS;

    void* args[] = {(void*)&x, (void*)&w1, (void*)&b1, (void*)&w2, (void*)&b2,
                    (void*)&out, (void*)&mean, (void*)&cnt};
    (void)hipLaunchCooperativeKernel((const void*)se_fused, dim3((int)G), dim3(256),
                                     args, 0, stream);
}

// Round 7
// 2347.038 us; speedup vs baseline: 3.2629x; 1.1503x over previous
//
#include <hip/hip_runtime.h>
#include <math.h>

#define Cdim 512
#define CRdim 32
#define Ldim 4096
#define Bdim 64
#define NROWS (Bdim * Cdim)   // 32768
#define CNT_STRIDE 32         // 128B per counter: no false sharing across batches

typedef float f32x4 __attribute__((ext_vector_type(4)));

// Single-pass SE: each block owns one (b,c) row per iteration.
//   1) stream row HBM->LDS (nt loads), reduce -> mean[row], release-add cnt[b]
//   2) RELAXED-spin until cnt[b]==512, then ONE acquire load (single L2 inv)
//   3) redundant tiny MLP from cached mean/weights -> s(b,c)
//   4) scale LDS row, nt-store to out
// x is read from HBM exactly once; no grid barrier; no per-poll cache inval.
__global__ __launch_bounds__(256) void se_fused(
        const float* __restrict__ x,
        const float* __restrict__ w1, const float* __restrict__ b1,
        const float* __restrict__ w2, const float* __restrict__ b2,
        float* __restrict__ out, float* __restrict__ mean,
        unsigned int* __restrict__ cnt)
{
    __shared__ float rowbuf[Ldim];         // 16 KiB
    __shared__ float red[4];
    __shared__ float hvec[CRdim];
    __shared__ float sval;

    const int t = threadIdx.x;
    const int G = gridDim.x;               // multiple of 512
    const int niter = (NROWS + G - 1) / G;

    for (int it = 0; it < niter; ++it) {
        const int row = it * G + blockIdx.x;
        if (row >= NROWS) continue;        // uniform per block
        const int b = row >> 9;
        const int c = row & 511;
        f32x4* rb = (f32x4*)rowbuf;

        // ---- phase 1: load + reduce ----
        const f32x4* xr = (const f32x4*)(x + (size_t)row * Ldim);
        float s = 0.f;
#pragma unroll
        for (int k = 0; k < 4; ++k) {
            f32x4 v = __builtin_nontemporal_load(&xr[t + k * 256]);
            rb[t + k * 256] = v;
            s += (v.x + v.y) + (v.z + v.w);
        }
#pragma unroll
        for (int off = 32; off > 0; off >>= 1) s += __shfl_down(s, off, 64);
        if ((t & 63) == 0) red[t >> 6] = s;
        __syncthreads();
        if (t == 0) {
            mean[row] = (red[0] + red[1] + red[2] + red[3]) * (1.0f / Ldim);
            unsigned int* ctr = &cnt[b * CNT_STRIDE];
            // release: mean[row] visible device-wide before the count bump
            __hip_atomic_fetch_add(ctr, 1u, __ATOMIC_RELEASE,
                                   __HIP_MEMORY_SCOPE_AGENT);
            // ---- phase 2: cheap relaxed poll (no cache maintenance) ----
            while (__hip_atomic_load(ctr, __ATOMIC_RELAXED,
                                     __HIP_MEMORY_SCOPE_AGENT) < (unsigned)Cdim)
                __builtin_amdgcn_s_sleep(8);
            // one-time acquire: single L1/L2 invalidate for this block
            (void)__hip_atomic_load(ctr, __ATOMIC_ACQUIRE,
                                    __HIP_MEMORY_SCOPE_AGENT);
        }
        __syncthreads();

        // ---- phase 3: redundant tiny MLP ----
        if (t < CRdim) {
            const f32x4* mv = (const f32x4*)(mean + b * Cdim);
            const f32x4* wv = (const f32x4*)(w1 + t * Cdim);
            f32x4 a0 = {0.f,0.f,0.f,0.f}, a1 = {0.f,0.f,0.f,0.f};
            f32x4 a2 = {0.f,0.f,0.f,0.f}, a3 = {0.f,0.f,0.f,0.f};
#pragma unroll
            for (int j = 0; j < 128; j += 4) {
                a0 += mv[j]   * wv[j];
                a1 += mv[j+1] * wv[j+1];
                a2 += mv[j+2] * wv[j+2];
                a3 += mv[j+3] * wv[j+3];
            }
            f32x4 a = (a0 + a1) + (a2 + a3);
            hvec[t] = fmaxf(b1[t] + (a.x + a.y) + (a.z + a.w), 0.f);
        }
        __syncthreads();
        if (t == 0) {
            float a = b2[c];
            const float* w2r = w2 + c * CRdim;
#pragma unroll
            for (int r = 0; r < CRdim; ++r) a = fmaf(hvec[r], w2r[r], a);
            sval = 1.0f / (1.0f + expf(-a));
        }
        __syncthreads();

        // ---- phase 4: scale + store ----
        const float sc = sval;
        f32x4* orow = (f32x4*)(out + (size_t)row * Ldim);
#pragma unroll
        for (int k = 0; k < 4; ++k) {
            f32x4 v = rb[t + k * 256];
            v *= sc;
            __builtin_nontemporal_store(v, &orow[t + k * 256]);
        }
        __syncthreads();                   // rowbuf reuse safety
    }
}

extern "C" void kernel_launch(void* const* d_in, const int* in_sizes, int n_in,
                              void* d_out, int out_size, void* d_ws, size_t ws_size,
                              hipStream_t stream) {
    const float* x  = (const float*)d_in[0];
    const float* w1 = (const float*)d_in[1];
    const float* b1 = (const float*)d_in[2];
    const float* w2 = (const float*)d_in[3];
    const float* b2 = (const float*)d_in[4];
    float* out  = (float*)d_out;

    float* mean = (float*)d_ws;                          // 32768 floats
    unsigned int* cnt = (unsigned int*)(mean + NROWS);   // 64 * 32 uints (8 KB)

    // counters must be zero at kernel start every call (ws is not re-poisoned)
    hipMemsetAsync(cnt, 0, Bdim * CNT_STRIDE * sizeof(unsigned int), stream);

    int bpc = 0;
    (void)hipOccupancyMaxActiveBlocksPerMultiprocessor(&bpc, (const void*)se_fused, 256, 0);
    if (bpc < 1) bpc = 1;
    hipDeviceProp_t prop;
    int dev = 0;
    (void)hipGetDevice(&dev);
    (void)hipGetDeviceProperties(&prop, dev);
    long long cap = (long long)bpc * prop.multiProcessorCount;
    long long G = (cap / 512) * 512;                     // whole batches per iteration
    if (G < 512) G = 512;
    if (G > NROWS) G = NROWS;

    void* args[] = {(void*)&x, (void*)&w1, (void*)&b1, (void*)&w2, (void*)&b2,
                    (void*)&out, (void*)&mean, (void*)&cnt};
    (void)hipLaunchCooperativeKernel((const void*)se_fused, dim3((int)G), dim3(256),
                                     args, 0, stream);
}

// Round 8
// 271.773 us; speedup vs baseline: 28.1788x; 8.6360x over previous
//
#include <hip/hip_runtime.h>
#include <math.h>

#define Cdim 512
#define CRdim 32
#define Ldim 4096
#define Bdim 64

typedef float f32x4 __attribute__((ext_vector_type(4)));

// ---------------- Kernel 1: per-(b,c) mean over L ----------------
// NT loads: probe MALL (hit the stable ~256MB resident slice of x) without
// churning the resident set.
__global__ __launch_bounds__(256) void se_reduce(const float* __restrict__ x,
                                                 float* __restrict__ mean) {
    const int row = blockIdx.x;               // b*C + c, 0..32767
    const f32x4* xr = reinterpret_cast<const f32x4*>(x + (size_t)row * Ldim);
    const int t = threadIdx.x;                // 256 threads, 1024 float4 per row
    float s = 0.0f;
#pragma unroll
    for (int k = 0; k < 4; ++k) {
        f32x4 v = __builtin_nontemporal_load(&xr[t + k * 256]);
        s += (v.x + v.y) + (v.z + v.w);
    }
#pragma unroll
    for (int off = 32; off > 0; off >>= 1) s += __shfl_down(s, off, 64);
    __shared__ float wsum[4];
    if ((t & 63) == 0) wsum[t >> 6] = s;
    __syncthreads();
    if (t == 0) {
        float tot = (wsum[0] + wsum[1]) + (wsum[2] + wsum[3]);
        mean[row] = tot * (1.0f / Ldim);
    }
}

// ---------------- Kernel 2: tiny MLP (relu -> sigmoid) ----------------
__global__ __launch_bounds__(512) void se_mlp(const float* __restrict__ mean,
                                              const float* __restrict__ w1,
                                              const float* __restrict__ b1,
                                              const float* __restrict__ w2,
                                              const float* __restrict__ b2,
                                              float* __restrict__ scale) {
    const int b = blockIdx.x;                 // 0..63
    const int t = threadIdx.x;                // 512 threads
    __shared__ float m[Cdim];
    __shared__ float h[CRdim];
    m[t] = mean[b * Cdim + t];
    __syncthreads();
    if (t < CRdim) {
        float acc = b1[t];
        const float* w1r = w1 + t * Cdim;
#pragma unroll 8
        for (int c = 0; c < Cdim; ++c) acc = fmaf(m[c], w1r[c], acc);
        h[t] = fmaxf(acc, 0.0f);
    }
    __syncthreads();
    float acc = b2[t];
    const float* w2r = w2 + t * CRdim;
#pragma unroll
    for (int r = 0; r < CRdim; ++r) acc = fmaf(h[r], w2r[r], acc);
    scale[b * Cdim + t] = 1.0f / (1.0f + expf(-acc));
}

// ---------------- Kernel 3: out = x * s[b,c] ----------------
// NT loads for x (stable MALL hits), NT stores for out (no MALL/L2 pollution).
__global__ __launch_bounds__(256) void se_scale(const float* __restrict__ x,
                                                const float* __restrict__ scale,
                                                float* __restrict__ out) {
    const int row = (Bdim * Cdim - 1) - blockIdx.x;      // reversed traversal
    const float s = scale[row];
    const f32x4* xr = reinterpret_cast<const f32x4*>(x + (size_t)row * Ldim);
    f32x4* orow = reinterpret_cast<f32x4*>(out + (size_t)row * Ldim);
    const int t = threadIdx.x;
#pragma unroll
    for (int k = 0; k < 4; ++k) {
        f32x4 v = __builtin_nontemporal_load(&xr[t + k * 256]);
        v *= s;
        __builtin_nontemporal_store(v, &orow[t + k * 256]);
    }
}

extern "C" void kernel_launch(void* const* d_in, const int* in_sizes, int n_in,
                              void* d_out, int out_size, void* d_ws, size_t ws_size,
                              hipStream_t stream) {
    const float* x  = (const float*)d_in[0];
    const float* w1 = (const float*)d_in[1];
    const float* b1 = (const float*)d_in[2];
    const float* w2 = (const float*)d_in[3];
    const float* b2 = (const float*)d_in[4];
    float* out = (float*)d_out;

    float* mean  = (float*)d_ws;                         // 64*512 floats
    float* scale = mean + (size_t)Bdim * Cdim;

    const int nrows = Bdim * Cdim;                       // 32768
    se_reduce<<<nrows, 256, 0, stream>>>(x, mean);
    se_mlp<<<Bdim, Cdim, 0, stream>>>(mean, w1, b1, w2, b2, scale);
    se_scale<<<nrows, 256, 0, stream>>>(x, scale, out);
}

// Round 9
// 266.061 us; speedup vs baseline: 28.7837x; 1.0215x over previous
//
#include <hip/hip_runtime.h>
#include <math.h>

#define Cdim 512
#define CRdim 32
#define Ldim 4096
#define Bdim 64

typedef float f32x4 __attribute__((ext_vector_type(4)));

// ---------------- Kernel 1: per-(b,c) mean over L ----------------
// Regular (allocating) loads measured fastest (R3 = 265.6us; nt loads R8 = 271.8us).
__global__ __launch_bounds__(256) void se_reduce(const float* __restrict__ x,
                                                 float* __restrict__ mean) {
    const int row = blockIdx.x;               // b*C + c, 0..32767
    const f32x4* xr = reinterpret_cast<const f32x4*>(x + (size_t)row * Ldim);
    const int t = threadIdx.x;                // 256 threads, 1024 float4 per row
    float s = 0.0f;
#pragma unroll
    for (int k = 0; k < 4; ++k) {
        f32x4 v = xr[t + k * 256];
        s += (v.x + v.y) + (v.z + v.w);
    }
#pragma unroll
    for (int off = 32; off > 0; off >>= 1) s += __shfl_down(s, off, 64);
    __shared__ float wsum[4];
    if ((t & 63) == 0) wsum[t >> 6] = s;
    __syncthreads();
    if (t == 0) {
        float tot = (wsum[0] + wsum[1]) + (wsum[2] + wsum[3]);
        mean[row] = tot * (1.0f / Ldim);
    }
}

// ---------------- Kernel 2: tiny MLP (relu -> sigmoid) ----------------
__global__ __launch_bounds__(512) void se_mlp(const float* __restrict__ mean,
                                              const float* __restrict__ w1,
                                              const float* __restrict__ b1,
                                              const float* __restrict__ w2,
                                              const float* __restrict__ b2,
                                              float* __restrict__ scale) {
    const int b = blockIdx.x;                 // 0..63
    const int t = threadIdx.x;                // 512 threads
    __shared__ float m[Cdim];
    __shared__ float h[CRdim];
    m[t] = mean[b * Cdim + t];
    __syncthreads();
    if (t < CRdim) {
        float acc = b1[t];
        const float* w1r = w1 + t * Cdim;
#pragma unroll 8
        for (int c = 0; c < Cdim; ++c) acc = fmaf(m[c], w1r[c], acc);
        h[t] = fmaxf(acc, 0.0f);
    }
    __syncthreads();
    float acc = b2[t];
    const float* w2r = w2 + t * CRdim;
#pragma unroll
    for (int r = 0; r < CRdim; ++r) acc = fmaf(h[r], w2r[r], acc);
    scale[b * Cdim + t] = 1.0f / (1.0f + expf(-acc));
}

// ---------------- Kernel 3: out = x * s[b,c] ----------------
// Reversed traversal (harmless) + non-temporal stores (measured +37us vs
// regular stores: keeps the 512MiB output stream out of L2/L3).
__global__ __launch_bounds__(256) void se_scale(const float* __restrict__ x,
                                                const float* __restrict__ scale,
                                                float* __restrict__ out) {
    const int row = (Bdim * Cdim - 1) - blockIdx.x;      // reversed traversal
    const float s = scale[row];
    const f32x4* xr = reinterpret_cast<const f32x4*>(x + (size_t)row * Ldim);
    f32x4* orow = reinterpret_cast<f32x4*>(out + (size_t)row * Ldim);
    const int t = threadIdx.x;
#pragma unroll
    for (int k = 0; k < 4; ++k) {
        f32x4 v = xr[t + k * 256];
        v *= s;
        __builtin_nontemporal_store(v, &orow[t + k * 256]);
    }
}

extern "C" void kernel_launch(void* const* d_in, const int* in_sizes, int n_in,
                              void* d_out, int out_size, void* d_ws, size_t ws_size,
                              hipStream_t stream) {
    const float* x  = (const float*)d_in[0];
    const float* w1 = (const float*)d_in[1];
    const float* b1 = (const float*)d_in[2];
    const float* w2 = (const float*)d_in[3];
    const float* b2 = (const float*)d_in[4];
    float* out = (float*)d_out;

    float* mean  = (float*)d_ws;                         // 64*512 floats
    float* scale = mean + (size_t)Bdim * Cdim;

    const int nrows = Bdim * Cdim;                       // 32768
    se_reduce<<<nrows, 256, 0, stream>>>(x, mean);
    se_mlp<<<Bdim, Cdim, 0, stream>>>(mean, w1, b1, w2, b2, scale);
    se_scale<<<nrows, 256, 0, stream>>>(x, scale, out);
}